// Round 9
// baseline (323.945 us; speedup 1.0000x reference)
//
#include <hip/hip_runtime.h>
#include <hip/hip_bf16.h>
#include <math.h>

#define S_LEN 2048
#define HIDW 2048
#define NHEAD 16
#define NKVH 4
#define HD 128
#define NB 2
#define MROWS (NB * S_LEN)                 // 4096
#define QKVN (NHEAD * HD + 2 * NKVH * HD)  // 3072
#define KOFF (NHEAD * HD)                  // 2048
#define VOFF (NHEAD * HD + NKVH * HD)      // 2560

typedef __bf16 bf16_t;
typedef __bf16 bf16x8_t __attribute__((ext_vector_type(8)));
typedef float f32x4_t __attribute__((ext_vector_type(4)));

__device__ __forceinline__ void gload_lds16(const bf16_t* g, bf16_t* l) {
  __builtin_amdgcn_global_load_lds(
      (const __attribute__((address_space(1))) void*)g,
      (__attribute__((address_space(3))) void*)l, 16, 0, 0);
}

__device__ __forceinline__ f32x4_t zero4() {
  f32x4_t z = {0.f, 0.f, 0.f, 0.f};
  return z;
}

__device__ __forceinline__ float fexp2(float x) {
#if __has_builtin(__builtin_amdgcn_exp2f)
  return __builtin_amdgcn_exp2f(x);
#else
  return exp2f(x);
#endif
}

// ---------------- convert x (f32 -> bf16), 8 elems/thread ----------------
__global__ __launch_bounds__(256) void k_cvt8(const float* __restrict__ in,
                                              bf16_t* __restrict__ out, int n8) {
  int i = blockIdx.x * 256 + threadIdx.x;
  if (i >= n8) return;
  const float4* p = (const float4*)(in + (size_t)i * 8);
  float4 a = p[0], b = p[1];
  bf16x8_t r;
  r[0] = (bf16_t)a.x; r[1] = (bf16_t)a.y; r[2] = (bf16_t)a.z; r[3] = (bf16_t)a.w;
  r[4] = (bf16_t)b.x; r[5] = (bf16_t)b.y; r[6] = (bf16_t)b.z; r[7] = (bf16_t)b.w;
  *(bf16x8_t*)(out + (size_t)i * 8) = r;
}

// ---------------- transpose + convert: in f32 [R][C] -> out bf16 [C][R] ----
__global__ __launch_bounds__(256) void k_tr_cvt(const float* __restrict__ in,
                                                bf16_t* __restrict__ out, int R, int C) {
  __shared__ float t[32][33];
  int c0 = blockIdx.x * 32, r0 = blockIdx.y * 32;
  int tx = threadIdx.x & 31, ty = threadIdx.x >> 5;
#pragma unroll
  for (int rr = ty; rr < 32; rr += 8) t[rr][tx] = in[(size_t)(r0 + rr) * C + c0 + tx];
  __syncthreads();
#pragma unroll
  for (int rr = ty; rr < 32; rr += 8)
    out[(size_t)(c0 + rr) * R + r0 + tx] = (bf16_t)t[tx][rr];
}

// ---------------- GEMM BMx256 tile (BM = BMH*128), BK=64, 8 waves ----------
template <int OUTF32, int BMH>
__global__ __launch_bounds__(512, 2) void k_gemm256(const bf16_t* __restrict__ A,
                                                    const bf16_t* __restrict__ Bt,
                                                    void* __restrict__ Cout,
                                                    int M, int N, int K, int nby) {
  __shared__ bf16_t As[2][BMH * 128 * 64];
  __shared__ bf16_t Bs[2][256 * 64];

  int tid = threadIdx.x;
  int lane = tid & 63, wid = tid >> 6;
  int l15 = lane & 15, lg = lane >> 4;
  int wrb = (wid >> 2) * (BMH * 64);  // wave M-offset (2 M-halves)
  int wcb = (wid & 3) * 64;           // wave N-offset (4 N-quarters)

  int nwg = gridDim.x;
  int qx = nwg >> 3;
  int lin = blockIdx.x;
  int wg = (lin & 7) * qx + (lin >> 3);
  int row0 = (wg / nby) * (BMH * 128), col0 = (wg % nby) * 256;

  int srow = tid >> 3;
  int scol = ((tid & 7) ^ (srow & 7)) * 8;
  const bf16_t* Ag = A + (size_t)(row0 + srow) * K + scol;
  const bf16_t* Bg = Bt + (size_t)(col0 + srow) * K + scol;

  f32x4_t acc[BMH * 4][4];
#pragma unroll
  for (int i = 0; i < BMH * 4; i++)
#pragma unroll
    for (int j = 0; j < 4; j++) acc[i][j] = zero4();

  int xr = (l15 & 7) << 4;

  // prologue: stage tile 0 -> buf 0
#pragma unroll
  for (int u = 0; u < BMH * 2; u++)
    gload_lds16(Ag + (size_t)u * 64 * K, As[0] + u * 4096 + tid * 8);
#pragma unroll
  for (int u = 0; u < 4; u++)
    gload_lds16(Bg + (size_t)u * 64 * K, Bs[0] + u * 4096 + tid * 8);
  asm volatile("s_waitcnt vmcnt(0)" ::: "memory");
  __builtin_amdgcn_s_barrier();
  __builtin_amdgcn_sched_barrier(0);

  int nk = K >> 6;
  for (int t = 0; t < nk; t++) {
    int cur = t & 1;
    const char* Ac = (const char*)As[cur];
    const char* Bc = (const char*)Bs[cur];
    bf16_t* An = As[cur ^ 1];
    bf16_t* Bn = Bs[cur ^ 1];
    const bf16_t* Agn = Ag + (size_t)(t + 1) * 64;
    const bf16_t* Bgn = Bg + (size_t)(t + 1) * 64;
    bool pf = (t + 1 < nk);

    bf16x8_t af[4][2];  // A-frags for current M-half, reused across N phases
#pragma unroll
    for (int ph = 0; ph < 4; ph++) {
      const int mh = (BMH == 2) ? (ph >> 1) : 0;
      const int nh = (BMH == 2) ? (ph & 1) : ph;
      const int NJ = (BMH == 2) ? 2 : 1;
      if ((BMH == 2) ? (nh == 0) : (ph == 0)) {
#pragma unroll
        for (int i = 0; i < 4; i++) {
          int row = wrb + (mh * 4 + i) * 16 + l15;
#pragma unroll
          for (int kk = 0; kk < 2; kk++)
            af[i][kk] = *(const bf16x8_t*)(Ac + ((row * 128 + kk * 64 + lg * 16) ^ xr));
        }
      }
      bf16x8_t bfr[NJ][2];
#pragma unroll
      for (int j = 0; j < NJ; j++) {
        int rowb = wcb + (nh * NJ + j) * 16 + l15;
#pragma unroll
        for (int kk = 0; kk < 2; kk++)
          bfr[j][kk] = *(const bf16x8_t*)(Bc + ((rowb * 128 + kk * 64 + lg * 16) ^ xr));
      }
      if (pf) {
        if (BMH == 2) {
          if (ph == 0) {
            gload_lds16(Agn, An + tid * 8);
            gload_lds16(Agn + (size_t)64 * K, An + 4096 + tid * 8);
            gload_lds16(Bgn, Bn + tid * 8);
          } else if (ph == 1) {
            gload_lds16(Agn + (size_t)128 * K, An + 8192 + tid * 8);
            gload_lds16(Agn + (size_t)192 * K, An + 12288 + tid * 8);
            gload_lds16(Bgn + (size_t)64 * K, Bn + 4096 + tid * 8);
          } else if (ph == 2) {
            gload_lds16(Bgn + (size_t)128 * K, Bn + 8192 + tid * 8);
            gload_lds16(Bgn + (size_t)192 * K, Bn + 12288 + tid * 8);
          }
        } else {
          if (ph == 0) {
            gload_lds16(Agn, An + tid * 8);
            gload_lds16(Agn + (size_t)64 * K, An + 4096 + tid * 8);
          } else if (ph == 1) {
            gload_lds16(Bgn, Bn + tid * 8);
            gload_lds16(Bgn + (size_t)64 * K, Bn + 4096 + tid * 8);
          } else if (ph == 2) {
            gload_lds16(Bgn + (size_t)128 * K, Bn + 8192 + tid * 8);
            gload_lds16(Bgn + (size_t)192 * K, Bn + 12288 + tid * 8);
          }
        }
      }
      __builtin_amdgcn_s_barrier();
      __builtin_amdgcn_s_setprio(1);
#pragma unroll
      for (int i = 0; i < 4; i++)
#pragma unroll
        for (int j = 0; j < NJ; j++)
#pragma unroll
          for (int kk = 0; kk < 2; kk++)
            acc[mh * 4 + i][nh * NJ + j] = __builtin_amdgcn_mfma_f32_16x16x32_bf16(
                af[i][kk], bfr[j][kk], acc[mh * 4 + i][nh * NJ + j], 0, 0, 0);
      __builtin_amdgcn_s_setprio(0);
      if (ph < 3) __builtin_amdgcn_s_barrier();
    }
    if (pf) asm volatile("s_waitcnt vmcnt(0)" ::: "memory");
    __builtin_amdgcn_s_barrier();
    __builtin_amdgcn_sched_barrier(0);
  }

#pragma unroll
  for (int i = 0; i < BMH * 4; i++) {
#pragma unroll
    for (int j = 0; j < 4; j++) {
      int r = row0 + wrb + i * 16 + lg * 4;
      int c = col0 + wcb + j * 16 + l15;
#pragma unroll
      for (int qd = 0; qd < 4; qd++) {
        if (OUTF32)
          ((float*)Cout)[(size_t)(r + qd) * N + c] = acc[i][j][qd];
        else
          ((bf16_t*)Cout)[(size_t)(r + qd) * N + c] = (bf16_t)acc[i][j][qd];
      }
    }
  }
}

// ---------------- RoPE (interleaved), in-place on qkv submatrix ------------
__global__ __launch_bounds__(256) void k_rope(bf16_t* __restrict__ buf,
                                              const float* __restrict__ cosT,
                                              const float* __restrict__ sinT,
                                              int ncols, float scale) {
  int idx = blockIdx.x * 256 + threadIdx.x;
  int perrow = ncols >> 3;
  int row = idx / perrow;
  int c8 = (idx - row * perrow) << 3;
  int s = row & (S_LEN - 1);
  int p0 = (c8 & (HD - 1)) >> 1;
  bf16_t* p = buf + (size_t)row * QKVN + c8;
  bf16x8_t v = *(const bf16x8_t*)p;
  bf16x8_t r;
#pragma unroll
  for (int t = 0; t < 4; t++) {
    float c = cosT[s * 64 + p0 + t];
    float sn = sinT[s * 64 + p0 + t];
    float te = (float)v[2 * t], to = (float)v[2 * t + 1];
    r[2 * t] = (bf16_t)((te * c - to * sn) * scale);
    r[2 * t + 1] = (bf16_t)((to * c + te * sn) * scale);
  }
  *(bf16x8_t*)p = r;
}

// ---------------- V -> Vt relayout: vt[b][kvh][d][s] -----------------------
__global__ __launch_bounds__(256) void k_vt(const bf16_t* __restrict__ qkv,
                                            bf16_t* __restrict__ vt) {
  __shared__ bf16_t t[32][33];
  int s0 = blockIdx.x * 32;
  int dt = (blockIdx.y & 3) * 32;
  int h = blockIdx.y >> 2;
  int b = blockIdx.z;
  int tx = threadIdx.x & 31, ty = threadIdx.x >> 5;
#pragma unroll
  for (int rr = ty; rr < 32; rr += 8)
    t[rr][tx] = qkv[(size_t)(b * S_LEN + s0 + rr) * QKVN + VOFF + h * HD + dt + tx];
  __syncthreads();
#pragma unroll
  for (int rr = ty; rr < 32; rr += 8)
    vt[((size_t)((b * NKVH + h) * HD + dt + rr)) * S_LEN + s0 + tx] = t[tx][rr];
}

// ---------------- flash attention: 4 waves, QBLK=64, single-buffer, 4/CU ---
// Occupancy play: 40 KB LDS (Ks 16K + Vs 16K + swizzled plds 8K) -> 4
// blocks/CU = 16 waves/CU. Single-buffered K/V: per tile {barrier; stage 8
// DMAs; barrier(drain); compute} — stage latency hidden by the other 3
// co-resident blocks (cross-block TLP replaces the intra-block dbuf, which
// cost 32 KB = half the occupancy). V stays in LDS (R7: L2-direct V thrashed,
// FETCH 30->171 MB). Boustrophedon qg map: co-resident {c,c+256,c+512,c+768}
// get qg {p,15-p,16+p,31-p} -> per-CU work sum == 66 uniform (no backfill
// slack exists at 4/CU, so residency-sum balance is what matters).
__global__ __launch_bounds__(256, 4) void k_attn(const bf16_t* __restrict__ qkv,
                                                 const bf16_t* __restrict__ vt,
                                                 bf16_t* __restrict__ ctx) {
  __shared__ bf16_t Ks[64 * 128];       // 16 KB, swizzled [kv][d]
  __shared__ bf16_t Vs[128 * 64];       // 16 KB, swizzled [d][kv]
  __shared__ bf16_t plds[4][16 * 64];   // 8 KB, XOR-swizzled, LD=64

  int tid = threadIdx.x;
  int lane = tid & 63, wid = tid >> 6;
  int idx = blockIdx.x;
  int bh = idx & 31;
  int p = (idx >> 5) & 7;
  int r = idx >> 8;
  int qg = (r == 0) ? p : (r == 1) ? (15 - p) : (r == 2) ? (16 + p) : (31 - p);
  int b = bh >> 4, h = bh & 15;
  int kvh = h >> 2;
  int q0 = qg * 64 + wid * 16;
  int l15 = lane & 15, lg = lane >> 4;

  const bf16_t* Kbase = qkv + (size_t)(b * S_LEN) * QKVN + KOFF + kvh * HD;
  const bf16_t* Vbase = vt + (size_t)(b * NKVH + kvh) * HD * S_LEN;

  const bf16_t* Qp = qkv + (size_t)(b * S_LEN + q0 + l15) * QKVN + h * HD + lg * 8;
  bf16x8_t aq[4];
#pragma unroll
  for (int kk = 0; kk < 4; kk++) aq[kk] = *(const bf16x8_t*)(Qp + kk * 32);

  int Ls[4], Lk[4], Lv[4];
#pragma unroll
  for (int u = 0; u < 4; u++) {
    int L = u * 4096 + tid * 16;
    Ls[u] = L >> 1;
    Lk[u] = L ^ (((L >> 8) & 7) << 4);
    Lv[u] = L ^ (((L >> 7) & 7) << 4);
  }

  f32x4_t o[8];
#pragma unroll
  for (int j = 0; j < 8; j++) o[j] = zero4();
  float m[4], lsum[4];
#pragma unroll
  for (int i = 0; i < 4; i++) { m[i] = -INFINITY; lsum[i] = 0.f; }

  char* pb = (char*)&plds[wid][0];
  int xr = (l15 & 7) << 4;
  int ntiles = qg + 1;

  for (int t = 0; t < ntiles; t++) {
    int kv0 = t * 64;
    const bf16_t* Kt = Kbase + (size_t)kv0 * QKVN;
    const bf16_t* Vt0 = Vbase + kv0;
    __syncthreads();  // all waves done reading previous tile
#pragma unroll
    for (int u = 0; u < 4; u++) {
      gload_lds16(Kt + (size_t)(Lk[u] >> 8) * QKVN + ((Lk[u] & 255) >> 1), Ks + Ls[u]);
      gload_lds16(Vt0 + (size_t)(Lv[u] >> 7) * S_LEN + ((Lv[u] & 127) >> 1), Vs + Ls[u]);
    }
    __syncthreads();  // DMA drained (implicit vmcnt(0) at barrier)

    const char* Kb = (const char*)Ks;
    const char* Vb = (const char*)Vs;

    // ---- QK^T ----
    f32x4_t sacc[4];
#pragma unroll
    for (int cg = 0; cg < 4; cg++) sacc[cg] = zero4();
    __builtin_amdgcn_s_setprio(1);
#pragma unroll
    for (int cg = 0; cg < 4; cg++) {
#pragma unroll
      for (int kk = 0; kk < 4; kk++) {
        int boff = ((cg * 16 + l15) * 256 + kk * 64 + lg * 16) ^ xr;
        bf16x8_t bk = *(const bf16x8_t*)(Kb + boff);
        sacc[cg] = __builtin_amdgcn_mfma_f32_16x16x32_bf16(aq[kk], bk, sacc[cg], 0, 0, 0);
      }
    }
    __builtin_amdgcn_s_setprio(0);
    if (kv0 + 63 > q0) {
#pragma unroll
      for (int cg = 0; cg < 4; cg++) {
        int col = kv0 + cg * 16 + l15;
#pragma unroll
        for (int i = 0; i < 4; i++) {
          int row = q0 + lg * 4 + i;
          if (col > row) sacc[cg][i] = -1e30f;
        }
      }
    }
    // ---- online softmax (base-2, defer-max) ----
    float pmax[4];
#pragma unroll
    for (int i = 0; i < 4; i++) {
      float v = fmaxf(fmaxf(sacc[0][i], sacc[1][i]), fmaxf(sacc[2][i], sacc[3][i]));
      v = fmaxf(v, __shfl_xor(v, 1));
      v = fmaxf(v, __shfl_xor(v, 2));
      v = fmaxf(v, __shfl_xor(v, 4));
      v = fmaxf(v, __shfl_xor(v, 8));
      pmax[i] = v;
    }
    float dm = fmaxf(fmaxf(pmax[0] - m[0], pmax[1] - m[1]),
                     fmaxf(pmax[2] - m[2], pmax[3] - m[3]));
    if (__any(dm > 8.0f)) {
#pragma unroll
      for (int i = 0; i < 4; i++) {
        float nm = fmaxf(m[i], pmax[i]);
        float sc = fexp2(m[i] - nm);
        m[i] = nm;
        lsum[i] *= sc;
#pragma unroll
        for (int j = 0; j < 8; j++) o[j][i] *= sc;
      }
    }
#pragma unroll
    for (int cg = 0; cg < 4; cg++)
#pragma unroll
      for (int i = 0; i < 4; i++) sacc[cg][i] = fexp2(sacc[cg][i] - m[i]);
#pragma unroll
    for (int i = 0; i < 4; i++) {
      float s = sacc[0][i] + sacc[1][i] + sacc[2][i] + sacc[3][i];
      s += __shfl_xor(s, 1);
      s += __shfl_xor(s, 2);
      s += __shfl_xor(s, 4);
      s += __shfl_xor(s, 8);
      lsum[i] += s;
    }
    // ---- P -> swizzled per-wave LDS -> A-fragments ----
#pragma unroll
    for (int cg = 0; cg < 4; cg++)
#pragma unroll
      for (int i = 0; i < 4; i++) {
        int row = lg * 4 + i;
        int byteoff = (row * 128 + (cg * 16 + l15) * 2) ^ ((row & 7) << 4);
        *(bf16_t*)(pb + byteoff) = (bf16_t)sacc[cg][i];
      }
    __builtin_amdgcn_wave_barrier();
    bf16x8_t pa0 = *(const bf16x8_t*)(pb + ((l15 * 128 + lg * 16) ^ ((l15 & 7) << 4)));
    bf16x8_t pa1 = *(const bf16x8_t*)(pb + ((l15 * 128 + 64 + lg * 16) ^ ((l15 & 7) << 4)));
    __builtin_amdgcn_wave_barrier();
    // ---- P.V ----
    __builtin_amdgcn_s_setprio(1);
#pragma unroll
    for (int j = 0; j < 8; j++) {
      int d = j * 16 + l15;
      int bo0 = (d * 128 + lg * 16) ^ xr;
      int bo1 = (d * 128 + 64 + lg * 16) ^ xr;
      o[j] = __builtin_amdgcn_mfma_f32_16x16x32_bf16(
          pa0, *(const bf16x8_t*)(Vb + bo0), o[j], 0, 0, 0);
      o[j] = __builtin_amdgcn_mfma_f32_16x16x32_bf16(
          pa1, *(const bf16x8_t*)(Vb + bo1), o[j], 0, 0, 0);
    }
    __builtin_amdgcn_s_setprio(0);
  }

  bf16_t* Cp = ctx + (size_t)(b * S_LEN + q0) * KOFF + h * HD;
#pragma unroll
  for (int i = 0; i < 4; i++) {
    float inv = 1.f / lsum[i];
    int row = lg * 4 + i;
#pragma unroll
    for (int j = 0; j < 8; j++)
      Cp[(size_t)row * KOFF + j * 16 + l15] = (bf16_t)(o[j][i] * inv);
  }
}

extern "C" void kernel_launch(void* const* d_in, const int* in_sizes, int n_in,
                              void* d_out, int out_size, void* d_ws, size_t ws_size,
                              hipStream_t stream) {
  const float* x = (const float*)d_in[0];
  const float* wq = (const float*)d_in[1];
  const float* wk = (const float*)d_in[2];
  const float* wv = (const float*)d_in[3];
  const float* wo = (const float*)d_in[4];
  const float* cosT = (const float*)d_in[5];
  const float* sinT = (const float*)d_in[6];

  bf16_t* xb = (bf16_t*)d_ws;                          // 4096x2048 (later reused as ctx)
  bf16_t* wqkvT = xb + (size_t)MROWS * HIDW;           // 3072x2048
  bf16_t* woT = wqkvT + (size_t)QKVN * HIDW;           // 2048x2048
  bf16_t* qkv = woT + (size_t)HIDW * HIDW;             // 4096x3072
  bf16_t* vtb = qkv + (size_t)MROWS * QKVN;            // 2*4*128*2048

  // 1) convert x
  k_cvt8<<<MROWS * HIDW / 8 / 256, 256, 0, stream>>>(x, xb, MROWS * HIDW / 8);
  // 2) weight transposes (f32 -> bf16, [K][N] -> [N][K])
  k_tr_cvt<<<dim3(KOFF / 32, HIDW / 32), 256, 0, stream>>>(wq, wqkvT, HIDW, KOFF);
  k_tr_cvt<<<dim3((NKVH * HD) / 32, HIDW / 32), 256, 0, stream>>>(
      wk, wqkvT + (size_t)KOFF * HIDW, HIDW, NKVH * HD);
  k_tr_cvt<<<dim3((NKVH * HD) / 32, HIDW / 32), 256, 0, stream>>>(
      wv, wqkvT + (size_t)VOFF * HIDW, HIDW, NKVH * HD);
  k_tr_cvt<<<dim3(HIDW / 32, KOFF / 32), 256, 0, stream>>>(wo, woT, KOFF, HIDW);
  // 3) QKV projection (256^2 tile, 192 blocks)
  k_gemm256<0, 2><<<(MROWS / 256) * (QKVN / 256), 512, 0, stream>>>(
      xb, wqkvT, qkv, MROWS, QKVN, HIDW, QKVN / 256);
  // 4) RoPE on q (fold rsqrt(D) * log2e for base-2 softmax) and k
  k_rope<<<MROWS * KOFF / 8 / 256, 256, 0, stream>>>(
      qkv, cosT, sinT, KOFF, 0.08838834764831845f * 1.4426950408889634f);
  k_rope<<<MROWS * (NKVH * HD) / 8 / 256, 256, 0, stream>>>(qkv + KOFF, cosT, sinT,
                                                            NKVH * HD, 1.0f);
  // 5) V transpose
  k_vt<<<dim3(S_LEN / 32, 4 * NKVH, NB), 256, 0, stream>>>(qkv, vtb);
  // 6) attention (ctx written into xb region — xb no longer needed)
  k_attn<<<32 * 32, 256, 0, stream>>>(qkv, vtb, xb);
  // 7) output projection -> f32 d_out (128x256 tile, 256 blocks = 100% fill)
  k_gemm256<1, 1><<<(MROWS / 128) * (HIDW / 256), 512, 0, stream>>>(
      xb, woT, d_out, MROWS, HIDW, KOFF, HIDW / 256);
}

// Round 10
// 232.847 us; speedup vs baseline: 1.3912x; 1.3912x over previous
//
#include <hip/hip_runtime.h>
#include <hip/hip_bf16.h>
#include <math.h>

#define S_LEN 2048
#define HIDW 2048
#define NHEAD 16
#define NKVH 4
#define HD 128
#define NB 2
#define MROWS (NB * S_LEN)                 // 4096
#define QKVN (NHEAD * HD + 2 * NKVH * HD)  // 3072
#define KOFF (NHEAD * HD)                  // 2048
#define VOFF (NHEAD * HD + NKVH * HD)      // 2560

typedef __bf16 bf16_t;
typedef __bf16 bf16x4_t __attribute__((ext_vector_type(4)));
typedef __bf16 bf16x8_t __attribute__((ext_vector_type(8)));
typedef float f32x4_t __attribute__((ext_vector_type(4)));

__device__ __forceinline__ void gload_lds16(const bf16_t* g, bf16_t* l) {
  __builtin_amdgcn_global_load_lds(
      (const __attribute__((address_space(1))) void*)g,
      (__attribute__((address_space(3))) void*)l, 16, 0, 0);
}

__device__ __forceinline__ f32x4_t zero4() {
  f32x4_t z = {0.f, 0.f, 0.f, 0.f};
  return z;
}

__device__ __forceinline__ float fexp2(float x) {
#if __has_builtin(__builtin_amdgcn_exp2f)
  return __builtin_amdgcn_exp2f(x);
#else
  return exp2f(x);
#endif
}

// ---------------- convert x (f32 -> bf16), 8 elems/thread ----------------
__global__ __launch_bounds__(256) void k_cvt8(const float* __restrict__ in,
                                              bf16_t* __restrict__ out, int n8) {
  int i = blockIdx.x * 256 + threadIdx.x;
  if (i >= n8) return;
  const float4* p = (const float4*)(in + (size_t)i * 8);
  float4 a = p[0], b = p[1];
  bf16x8_t r;
  r[0] = (bf16_t)a.x; r[1] = (bf16_t)a.y; r[2] = (bf16_t)a.z; r[3] = (bf16_t)a.w;
  r[4] = (bf16_t)b.x; r[5] = (bf16_t)b.y; r[6] = (bf16_t)b.z; r[7] = (bf16_t)b.w;
  *(bf16x8_t*)(out + (size_t)i * 8) = r;
}

// ---------------- transpose + convert: in f32 [R][C] -> out bf16 [C][R] ----
__global__ __launch_bounds__(256) void k_tr_cvt(const float* __restrict__ in,
                                                bf16_t* __restrict__ out, int R, int C) {
  __shared__ float t[32][33];
  int c0 = blockIdx.x * 32, r0 = blockIdx.y * 32;
  int tx = threadIdx.x & 31, ty = threadIdx.x >> 5;
#pragma unroll
  for (int rr = ty; rr < 32; rr += 8) t[rr][tx] = in[(size_t)(r0 + rr) * C + c0 + tx];
  __syncthreads();
#pragma unroll
  for (int rr = ty; rr < 32; rr += 8)
    out[(size_t)(c0 + rr) * R + r0 + tx] = (bf16_t)t[tx][rr];
}

// ---------------- GEMM BMx256 tile (BM = BMH*128), BK=64, 8 waves ----------
// EPI=0: f32 plain out. EPI=2: fused QKV epilogue — rope'd bf16 Q/K written
// to Cout (qkv), V columns (>=VOFF, block-aligned) written TRANSPOSED to
// vt[b][kvh][d][s]. Rope pair exchange via __shfl_xor(.,1): partner column
// c^1 lives in lane^1 (c = ...+l15). cos/sin tables L1-resident.
template <int EPI, int BMH>
__global__ __launch_bounds__(512, 2) void k_gemm256(const bf16_t* __restrict__ A,
                                                    const bf16_t* __restrict__ Bt,
                                                    void* __restrict__ Cout,
                                                    int M, int N, int K, int nby,
                                                    const float* __restrict__ cosT,
                                                    const float* __restrict__ sinT,
                                                    bf16_t* __restrict__ vt) {
  __shared__ bf16_t As[2][BMH * 128 * 64];
  __shared__ bf16_t Bs[2][256 * 64];

  int tid = threadIdx.x;
  int lane = tid & 63, wid = tid >> 6;
  int l15 = lane & 15, lg = lane >> 4;
  int wrb = (wid >> 2) * (BMH * 64);  // wave M-offset (2 M-halves)
  int wcb = (wid & 3) * 64;           // wave N-offset (4 N-quarters)

  int nwg = gridDim.x;
  int qx = nwg >> 3;
  int lin = blockIdx.x;
  int wg = (lin & 7) * qx + (lin >> 3);
  int row0 = (wg / nby) * (BMH * 128), col0 = (wg % nby) * 256;

  int srow = tid >> 3;
  int scol = ((tid & 7) ^ (srow & 7)) * 8;
  const bf16_t* Ag = A + (size_t)(row0 + srow) * K + scol;
  const bf16_t* Bg = Bt + (size_t)(col0 + srow) * K + scol;

  f32x4_t acc[BMH * 4][4];
#pragma unroll
  for (int i = 0; i < BMH * 4; i++)
#pragma unroll
    for (int j = 0; j < 4; j++) acc[i][j] = zero4();

  int xr = (l15 & 7) << 4;

  // prologue: stage tile 0 -> buf 0
#pragma unroll
  for (int u = 0; u < BMH * 2; u++)
    gload_lds16(Ag + (size_t)u * 64 * K, As[0] + u * 4096 + tid * 8);
#pragma unroll
  for (int u = 0; u < 4; u++)
    gload_lds16(Bg + (size_t)u * 64 * K, Bs[0] + u * 4096 + tid * 8);
  asm volatile("s_waitcnt vmcnt(0)" ::: "memory");
  __builtin_amdgcn_s_barrier();
  __builtin_amdgcn_sched_barrier(0);

  int nk = K >> 6;
  for (int t = 0; t < nk; t++) {
    int cur = t & 1;
    const char* Ac = (const char*)As[cur];
    const char* Bc = (const char*)Bs[cur];
    bf16_t* An = As[cur ^ 1];
    bf16_t* Bn = Bs[cur ^ 1];
    const bf16_t* Agn = Ag + (size_t)(t + 1) * 64;
    const bf16_t* Bgn = Bg + (size_t)(t + 1) * 64;
    bool pf = (t + 1 < nk);

    bf16x8_t af[4][2];  // A-frags for current M-half, reused across N phases
#pragma unroll
    for (int ph = 0; ph < 4; ph++) {
      const int mh = (BMH == 2) ? (ph >> 1) : 0;
      const int nh = (BMH == 2) ? (ph & 1) : ph;
      const int NJ = (BMH == 2) ? 2 : 1;
      if ((BMH == 2) ? (nh == 0) : (ph == 0)) {
#pragma unroll
        for (int i = 0; i < 4; i++) {
          int row = wrb + (mh * 4 + i) * 16 + l15;
#pragma unroll
          for (int kk = 0; kk < 2; kk++)
            af[i][kk] = *(const bf16x8_t*)(Ac + ((row * 128 + kk * 64 + lg * 16) ^ xr));
        }
      }
      bf16x8_t bfr[NJ][2];
#pragma unroll
      for (int j = 0; j < NJ; j++) {
        int rowb = wcb + (nh * NJ + j) * 16 + l15;
#pragma unroll
        for (int kk = 0; kk < 2; kk++)
          bfr[j][kk] = *(const bf16x8_t*)(Bc + ((rowb * 128 + kk * 64 + lg * 16) ^ xr));
      }
      if (pf) {
        if (BMH == 2) {
          if (ph == 0) {
            gload_lds16(Agn, An + tid * 8);
            gload_lds16(Agn + (size_t)64 * K, An + 4096 + tid * 8);
            gload_lds16(Bgn, Bn + tid * 8);
          } else if (ph == 1) {
            gload_lds16(Agn + (size_t)128 * K, An + 8192 + tid * 8);
            gload_lds16(Agn + (size_t)192 * K, An + 12288 + tid * 8);
            gload_lds16(Bgn + (size_t)64 * K, Bn + 4096 + tid * 8);
          } else if (ph == 2) {
            gload_lds16(Bgn + (size_t)128 * K, Bn + 8192 + tid * 8);
            gload_lds16(Bgn + (size_t)192 * K, Bn + 12288 + tid * 8);
          }
        } else {
          if (ph == 0) {
            gload_lds16(Agn, An + tid * 8);
            gload_lds16(Agn + (size_t)64 * K, An + 4096 + tid * 8);
          } else if (ph == 1) {
            gload_lds16(Bgn, Bn + tid * 8);
            gload_lds16(Bgn + (size_t)64 * K, Bn + 4096 + tid * 8);
          } else if (ph == 2) {
            gload_lds16(Bgn + (size_t)128 * K, Bn + 8192 + tid * 8);
            gload_lds16(Bgn + (size_t)192 * K, Bn + 12288 + tid * 8);
          }
        }
      }
      __builtin_amdgcn_s_barrier();
      __builtin_amdgcn_s_setprio(1);
#pragma unroll
      for (int i = 0; i < 4; i++)
#pragma unroll
        for (int j = 0; j < NJ; j++)
#pragma unroll
          for (int kk = 0; kk < 2; kk++)
            acc[mh * 4 + i][nh * NJ + j] = __builtin_amdgcn_mfma_f32_16x16x32_bf16(
                af[i][kk], bfr[j][kk], acc[mh * 4 + i][nh * NJ + j], 0, 0, 0);
      __builtin_amdgcn_s_setprio(0);
      if (ph < 3) __builtin_amdgcn_s_barrier();
    }
    if (pf) asm volatile("s_waitcnt vmcnt(0)" ::: "memory");
    __builtin_amdgcn_s_barrier();
    __builtin_amdgcn_sched_barrier(0);
  }

  if (EPI == 2) {
    const float QS = 0.08838834764831845f * 1.4426950408889634f;
#pragma unroll
    for (int i = 0; i < BMH * 4; i++) {
#pragma unroll
      for (int j = 0; j < 4; j++) {
        int c = col0 + wcb + j * 16 + l15;
        int rbase = row0 + wrb + i * 16 + lg * 4;
        if (c < VOFF) {
          // rope: partner column c^1 is in lane^1 (block-uniform branch)
          float scale = (c < KOFF) ? QS : 1.0f;
          int p0 = (c & 127) >> 1;
          int codd = c & 1;
#pragma unroll
          for (int qd = 0; qd < 4; qd++) {
            int rr = rbase + qd;
            int s = rr & (S_LEN - 1);
            float self = acc[i][j][qd];
            float other = __shfl_xor(self, 1);
            float cv = cosT[s * 64 + p0], sv = sinT[s * 64 + p0];
            float outv = codd ? (self * cv + other * sv) : (self * cv - other * sv);
            ((bf16_t*)Cout)[(size_t)rr * N + c] = (bf16_t)(outv * scale);
          }
        } else {
          // V: write transposed to vt[b][kvh][d][s], 4 contiguous s per store
          int dcol = c - VOFF;
          int kvh = dcol >> 7, d = dcol & 127;
          int bb = rbase >> 11;
          int sbase = rbase & (S_LEN - 1);
          bf16x4_t pk;
#pragma unroll
          for (int qd = 0; qd < 4; qd++) pk[qd] = (bf16_t)acc[i][j][qd];
          *(bf16x4_t*)(vt + ((size_t)((bb * NKVH + kvh) * HD + d)) * S_LEN + sbase) = pk;
        }
      }
    }
  } else {
#pragma unroll
    for (int i = 0; i < BMH * 4; i++) {
#pragma unroll
      for (int j = 0; j < 4; j++) {
        int r = row0 + wrb + i * 16 + lg * 4;
        int c = col0 + wcb + j * 16 + l15;
#pragma unroll
        for (int qd = 0; qd < 4; qd++)
          ((float*)Cout)[(size_t)(r + qd) * N + c] = acc[i][j][qd];
      }
    }
  }
}

// ---------------- flash attention: 4 waves, QBLK=64, 2-phase pipeline ------
// R8-measured version (96.9 us): K AND V double-buffered in LDS (73 KB ->
// 2 blocks/CU), LPT dispatch. R9 taught: single-buffer/4-per-CU is WORSE
// (182 us) — the stage drain lands on every tile's critical path and all
// co-resident blocks stall in lockstep. Pipeline depth > occupancy here.
__global__ __launch_bounds__(256, 2) void k_attn(const bf16_t* __restrict__ qkv,
                                                 const bf16_t* __restrict__ vt,
                                                 bf16_t* __restrict__ ctx) {
  __shared__ bf16_t Ks[2 * 64 * 128];   // 2 x 16 KB, swizzled [kv][d]
  __shared__ bf16_t Vs[2 * 128 * 64];   // 2 x 16 KB, swizzled [d][kv]
  __shared__ bf16_t plds[4][16 * 72];

  int tid = threadIdx.x;
  int lane = tid & 63, wid = tid >> 6;
  int idx = blockIdx.x;
  int bh = idx & 31;
  int qg = 31 - (idx >> 5);        // longest-first dispatch (LPT backfill)
  int b = bh >> 4, h = bh & 15;
  int kvh = h >> 2;
  int q0 = qg * 64 + wid * 16;
  int l15 = lane & 15, lg = lane >> 4;

  const bf16_t* Kbase = qkv + (size_t)(b * S_LEN) * QKVN + KOFF + kvh * HD;
  const bf16_t* Vbase = vt + (size_t)(b * NKVH + kvh) * HD * S_LEN;

  const bf16_t* Qp = qkv + (size_t)(b * S_LEN + q0 + l15) * QKVN + h * HD + lg * 8;
  bf16x8_t aq[4];
#pragma unroll
  for (int kk = 0; kk < 4; kk++) aq[kk] = *(const bf16x8_t*)(Qp + kk * 32);

  int Ls[4], Lk[4], Lv[4];
#pragma unroll
  for (int u = 0; u < 4; u++) {
    int L = u * 4096 + tid * 16;
    Ls[u] = L >> 1;
    Lk[u] = L ^ (((L >> 8) & 7) << 4);
    Lv[u] = L ^ (((L >> 7) & 7) << 4);
  }

  f32x4_t o[8];
#pragma unroll
  for (int j = 0; j < 8; j++) o[j] = zero4();
  float m[4], lsum[4];
#pragma unroll
  for (int i = 0; i < 4; i++) { m[i] = -INFINITY; lsum[i] = 0.f; }

  bf16_t* pbuf = &plds[wid][0];
  int xr = (l15 & 7) << 4;
  int ntiles = qg + 1;

#pragma unroll
  for (int u = 0; u < 4; u++) {
    gload_lds16(Kbase + (size_t)(Lk[u] >> 8) * QKVN + ((Lk[u] & 255) >> 1), Ks + Ls[u]);
    gload_lds16(Vbase + (size_t)(Lv[u] >> 7) * S_LEN + ((Lv[u] & 127) >> 1), Vs + Ls[u]);
  }
  __syncthreads();

  for (int t = 0; t < ntiles; t++) {
    int kv0 = t * 64;
    if (t + 1 < ntiles) {
      const bf16_t* Kn = Kbase + (size_t)(kv0 + 64) * QKVN;
      const bf16_t* Vn = Vbase + kv0 + 64;
      int bo = ((t + 1) & 1) * 8192;
#pragma unroll
      for (int u = 0; u < 4; u++) {
        gload_lds16(Kn + (size_t)(Lk[u] >> 8) * QKVN + ((Lk[u] & 255) >> 1), Ks + bo + Ls[u]);
        gload_lds16(Vn + (size_t)(Lv[u] >> 7) * S_LEN + ((Lv[u] & 127) >> 1), Vs + bo + Ls[u]);
      }
    }
    const char* Kb = (const char*)Ks + (t & 1) * 16384;
    const char* Vb = (const char*)Vs + (t & 1) * 16384;

    f32x4_t sacc[4];
#pragma unroll
    for (int cg = 0; cg < 4; cg++) sacc[cg] = zero4();
#pragma unroll
    for (int cg = 0; cg < 4; cg++) {
#pragma unroll
      for (int kk = 0; kk < 4; kk++) {
        int boff = ((cg * 16 + l15) * 256 + kk * 64 + lg * 16) ^ xr;
        bf16x8_t bk = *(const bf16x8_t*)(Kb + boff);
        sacc[cg] = __builtin_amdgcn_mfma_f32_16x16x32_bf16(aq[kk], bk, sacc[cg], 0, 0, 0);
      }
    }
    if (kv0 + 63 > q0) {
#pragma unroll
      for (int cg = 0; cg < 4; cg++) {
        int col = kv0 + cg * 16 + l15;
#pragma unroll
        for (int i = 0; i < 4; i++) {
          int row = q0 + lg * 4 + i;
          if (col > row) sacc[cg][i] = -1e30f;
        }
      }
    }
    float pmax[4];
#pragma unroll
    for (int i = 0; i < 4; i++) {
      float v = fmaxf(fmaxf(sacc[0][i], sacc[1][i]), fmaxf(sacc[2][i], sacc[3][i]));
      v = fmaxf(v, __shfl_xor(v, 1));
      v = fmaxf(v, __shfl_xor(v, 2));
      v = fmaxf(v, __shfl_xor(v, 4));
      v = fmaxf(v, __shfl_xor(v, 8));
      pmax[i] = v;
    }
    float dm = fmaxf(fmaxf(pmax[0] - m[0], pmax[1] - m[1]),
                     fmaxf(pmax[2] - m[2], pmax[3] - m[3]));
    if (__any(dm > 8.0f)) {
#pragma unroll
      for (int i = 0; i < 4; i++) {
        float nm = fmaxf(m[i], pmax[i]);
        float sc = fexp2(m[i] - nm);
        m[i] = nm;
        lsum[i] *= sc;
#pragma unroll
        for (int j = 0; j < 8; j++) o[j][i] *= sc;
      }
    }
#pragma unroll
    for (int cg = 0; cg < 4; cg++)
#pragma unroll
      for (int i = 0; i < 4; i++) sacc[cg][i] = fexp2(sacc[cg][i] - m[i]);
#pragma unroll
    for (int i = 0; i < 4; i++) {
      float s = sacc[0][i] + sacc[1][i] + sacc[2][i] + sacc[3][i];
      s += __shfl_xor(s, 1);
      s += __shfl_xor(s, 2);
      s += __shfl_xor(s, 4);
      s += __shfl_xor(s, 8);
      lsum[i] += s;
    }
#pragma unroll
    for (int cg = 0; cg < 4; cg++)
#pragma unroll
      for (int i = 0; i < 4; i++)
        pbuf[(lg * 4 + i) * 72 + cg * 16 + l15] = (bf16_t)sacc[cg][i];
    __builtin_amdgcn_wave_barrier();
    bf16x8_t pa0 = *(const bf16x8_t*)(pbuf + l15 * 72 + lg * 8);
    bf16x8_t pa1 = *(const bf16x8_t*)(pbuf + l15 * 72 + 32 + lg * 8);
    __builtin_amdgcn_wave_barrier();
#pragma unroll
    for (int j = 0; j < 8; j++) {
      int d = j * 16 + l15;
      int bo0 = (d * 128 + lg * 16) ^ xr;
      int bo1 = (d * 128 + 64 + lg * 16) ^ xr;
      o[j] = __builtin_amdgcn_mfma_f32_16x16x32_bf16(
          pa0, *(const bf16x8_t*)(Vb + bo0), o[j], 0, 0, 0);
      o[j] = __builtin_amdgcn_mfma_f32_16x16x32_bf16(
          pa1, *(const bf16x8_t*)(Vb + bo1), o[j], 0, 0, 0);
    }
    __syncthreads();
  }

  bf16_t* Cp = ctx + (size_t)(b * S_LEN + q0) * KOFF + h * HD;
#pragma unroll
  for (int i = 0; i < 4; i++) {
    float inv = 1.f / lsum[i];
    int row = lg * 4 + i;
#pragma unroll
    for (int j = 0; j < 8; j++)
      Cp[(size_t)row * KOFF + j * 16 + l15] = (bf16_t)(o[j][i] * inv);
  }
}

extern "C" void kernel_launch(void* const* d_in, const int* in_sizes, int n_in,
                              void* d_out, int out_size, void* d_ws, size_t ws_size,
                              hipStream_t stream) {
  const float* x = (const float*)d_in[0];
  const float* wq = (const float*)d_in[1];
  const float* wk = (const float*)d_in[2];
  const float* wv = (const float*)d_in[3];
  const float* wo = (const float*)d_in[4];
  const float* cosT = (const float*)d_in[5];
  const float* sinT = (const float*)d_in[6];

  bf16_t* xb = (bf16_t*)d_ws;                          // 4096x2048 (later reused as ctx)
  bf16_t* wqkvT = xb + (size_t)MROWS * HIDW;           // 3072x2048
  bf16_t* woT = wqkvT + (size_t)QKVN * HIDW;           // 2048x2048
  bf16_t* qkv = woT + (size_t)HIDW * HIDW;             // 4096x3072
  bf16_t* vtb = qkv + (size_t)MROWS * QKVN;            // 2*4*128*2048

  // 1) convert x
  k_cvt8<<<MROWS * HIDW / 8 / 256, 256, 0, stream>>>(x, xb, MROWS * HIDW / 8);
  // 2) weight transposes (f32 -> bf16, [K][N] -> [N][K])
  k_tr_cvt<<<dim3(KOFF / 32, HIDW / 32), 256, 0, stream>>>(wq, wqkvT, HIDW, KOFF);
  k_tr_cvt<<<dim3((NKVH * HD) / 32, HIDW / 32), 256, 0, stream>>>(
      wk, wqkvT + (size_t)KOFF * HIDW, HIDW, NKVH * HD);
  k_tr_cvt<<<dim3((NKVH * HD) / 32, HIDW / 32), 256, 0, stream>>>(
      wv, wqkvT + (size_t)VOFF * HIDW, HIDW, NKVH * HD);
  k_tr_cvt<<<dim3(HIDW / 32, KOFF / 32), 256, 0, stream>>>(wo, woT, KOFF, HIDW);
  // 3) QKV projection with FUSED rope (Q scaled for base-2 softmax) + V
  //    transpose epilogue (replaces k_rope x2 and k_vt)
  k_gemm256<2, 2><<<(MROWS / 256) * (QKVN / 256), 512, 0, stream>>>(
      xb, wqkvT, qkv, MROWS, QKVN, HIDW, QKVN / 256, cosT, sinT, vtb);
  // 4) attention (ctx written into xb region — xb no longer needed)
  k_attn<<<32 * 32, 256, 0, stream>>>(qkv, vtb, xb);
  // 5) output projection -> f32 d_out (128x256 tile, 256 blocks = 100% fill)
  k_gemm256<0, 1><<<(MROWS / 128) * (HIDW / 256), 512, 0, stream>>>(
      xb, woT, d_out, MROWS, HIDW, KOFF, HIDW / 256, nullptr, nullptr, nullptr);
}